// Round 10
// baseline (522.247 us; speedup 1.0000x reference)
//
#include <hip/hip_runtime.h>
#include <math.h>

#define NL 4
#define DIM 512
#define NH 32
#define DHD 16
#define SEQ 1024
#define NB 2
#define LN_EPS 1e-5f
#define NEGF (-1e30f)
#define QSC 0.36067376022224085f   // 0.25 * log2(e), folded into Wq/bq

typedef _Float16 half4 __attribute__((ext_vector_type(4)));
typedef _Float16 half8 __attribute__((ext_vector_type(8)));
typedef float floatx4 __attribute__((ext_vector_type(4)));

__device__ __forceinline__ float gelu_exact(float x) {
    return 0.5f * x * (1.0f + erff(x * 0.70710678118654752f));
}

// async global->LDS, 16 B per lane; LDS base wave-uniform, lane i lands at base + i*16
__device__ __forceinline__ void async16(const void* g, void* l) {
    __builtin_amdgcn_global_load_lds(
        (const __attribute__((address_space(1))) void*)g,
        (__attribute__((address_space(3))) void*)l, 16, 0, 0);
}

// ---------------------------------------------------------------- fused prep: weights^T f16 + biases + Er f16 + init
__global__ __launch_bounds__(256) void k_prep_all(const float* __restrict__ Wq,
        const float* __restrict__ Wk, const float* __restrict__ Wv,
        const float* __restrict__ Wlin, const float* __restrict__ bq,
        const float* __restrict__ bk, const float* __restrict__ bv,
        const float* __restrict__ Er, const float* __restrict__ x,
        const float* __restrict__ Wi, const float* __restrict__ bi,
        _Float16* __restrict__ Wqkvt, _Float16* __restrict__ Wlint,
        float* __restrict__ bqkv, _Float16* __restrict__ Erh,
        float* __restrict__ h, _Float16* __restrict__ hf) {
    __shared__ _Float16 lt[64][72];
    const int u = blockIdx.x;
    const int tid = threadIdx.x;
    if (u < 1024) {                       // ---- weight transpose-convert
        const int kx = u & 7, ny = (u >> 3) & 7, mz = u >> 6;
        const int l = mz >> 2, which = mz & 3;
        const float* src = (which == 0) ? Wq : (which == 1) ? Wk : (which == 2) ? Wv : Wlin;
        src += (size_t)l * 262144;
        const float scale = (which == 0) ? QSC : 1.0f;
        _Float16* dst = (which < 3) ? (Wqkvt + (size_t)l * 786432 + (size_t)which * 262144)
                                    : (Wlint + (size_t)l * 262144);
        const int k0 = kx << 6, n0 = ny << 6;
        #pragma unroll
        for (int p = 0; p < 4; p++) {
            int kl = (p << 4) + (tid >> 4);
            int n4 = (tid & 15) << 2;
            float4 wv = *(const float4*)(src + (size_t)(k0 + kl) * 512 + n0 + n4);
            lt[n4 + 0][kl] = (_Float16)(wv.x * scale);
            lt[n4 + 1][kl] = (_Float16)(wv.y * scale);
            lt[n4 + 2][kl] = (_Float16)(wv.z * scale);
            lt[n4 + 3][kl] = (_Float16)(wv.w * scale);
        }
        __syncthreads();
        int nl = tid >> 2, k16 = (tid & 3) << 4;
        float4* d4 = (float4*)(dst + (size_t)(n0 + nl) * 512 + k0 + k16);
        const float4* s4 = (const float4*)&lt[nl][k16];
        d4[0] = s4[0];
        d4[1] = s4[1];
    } else if (u < 2048) {                // ---- init: h = gelu(x*Wi + bi), + f16 copy
        int idx0 = ((u - 1024) << 10) + (tid << 2);
        int d = idx0 & 511, bs = idx0 >> 9;
        float xs = x[bs];
        float4 wv = *(const float4*)(Wi + d);
        float4 bv = *(const float4*)(bi + d);
        float4 r;
        r.x = gelu_exact(xs * wv.x + bv.x);
        r.y = gelu_exact(xs * wv.y + bv.y);
        r.z = gelu_exact(xs * wv.z + bv.z);
        r.w = gelu_exact(xs * wv.w + bv.w);
        *(float4*)(h + idx0) = r;
        half4 rh = {(_Float16)r.x, (_Float16)r.y, (_Float16)r.z, (_Float16)r.w};
        *(half4*)(hf + idx0) = rh;
    } else {                              // ---- biases (bq scaled) + Er f16
        int idx = ((u - 2048) << 8) + tid;
        if (idx < NL * 1536) {
            int l = idx / 1536, j = idx % 1536;
            int which = j >> 9, jj = j & 511;
            float val = (which == 0) ? bq[l * 512 + jj] * QSC
                      : (which == 1) ? bk[l * 512 + jj] : bv[l * 512 + jj];
            bqkv[idx] = val;
        }
        int e = idx - NL * 1536;
        if (e >= 0 && e < NL * SEQ * DHD) Erh[e] = (_Float16)Er[e];
    }
}

// ---------------------------------------------------------------- qkv GEMM: 128x96 tile, BK=64, async panels
__global__ __launch_bounds__(256) void k_gemm_qkv(const _Float16* __restrict__ A,
        const _Float16* __restrict__ Bt, const float* __restrict__ bias,
        _Float16* __restrict__ o16) {
    __shared__ _Float16 As[2][128][32];   // 16 KB
    __shared__ _Float16 Bs[2][96][32];    // 12 KB
    const int tid = threadIdx.x;
    const int w = tid >> 6, lane = tid & 63;
    const int nn = lane & 15, qd = lane >> 4;
    const int wm = (w & 1) << 6;          // 0 / 64
    const int wn = (w >> 1) * 48;         // 0 / 48
    const int m0 = blockIdx.x << 7;
    const int n0 = blockIdx.y * 96;
    const int srow = lane >> 2, scol = (lane & 3) << 3;
    floatx4 acc[4][3] = {};
    for (int k0 = 0; k0 < 512; k0 += 64) {
        __syncthreads();
        #pragma unroll
        for (int p = 0; p < 2; p++) {
            #pragma unroll
            for (int hh = 0; hh < 2; hh++)
                async16(A + (size_t)(m0 + (hh << 6) + (w << 4) + srow) * 512
                          + k0 + (p << 5) + scol,
                        &As[p][(hh << 6) + (w << 4)][0]);
            async16(Bt + (size_t)(n0 + (w << 4) + srow) * 512 + k0 + (p << 5) + scol,
                    &Bs[p][(w << 4)][0]);
            if (w < 2)
                async16(Bt + (size_t)(n0 + 64 + (w << 4) + srow) * 512
                           + k0 + (p << 5) + scol,
                        &Bs[p][64 + (w << 4)][0]);
        }
        __syncthreads();
        #pragma unroll
        for (int ks = 0; ks < 2; ks++) {
            half8 af[4], bf[3];
            #pragma unroll
            for (int t = 0; t < 4; t++)
                af[t] = *(const half8*)&As[ks][wm + (t << 4) + nn][qd << 3];
            #pragma unroll
            for (int t = 0; t < 3; t++)
                bf[t] = *(const half8*)&Bs[ks][wn + (t << 4) + nn][qd << 3];
            #pragma unroll
            for (int ti = 0; ti < 4; ti++)
                #pragma unroll
                for (int tj = 0; tj < 3; tj++)
                    acc[ti][tj] = __builtin_amdgcn_mfma_f32_16x16x32_f16(
                            af[ti], bf[tj], acc[ti][tj], 0, 0, 0);
        }
    }
    float bv3[3];
    #pragma unroll
    for (int tj = 0; tj < 3; tj++) bv3[tj] = bias[n0 + wn + (tj << 4) + nn];
    #pragma unroll
    for (int ti = 0; ti < 4; ti++) {
        int rg = m0 + wm + (ti << 4) + (qd << 2);
        #pragma unroll
        for (int tj = 0; tj < 3; tj++) {
            int colg = n0 + wn + (tj << 4) + nn;
            int which = colg >> 9, ci = colg & 511;
            _Float16* op = o16 + (size_t)which * 1048576 + (size_t)rg * 512 + ci;
            #pragma unroll
            for (int r = 0; r < 4; r++)
                op[(size_t)r * 512] = (_Float16)(acc[ti][tj][r] + bv3[tj]);
        }
    }
}

// ---------------------------------------------------------------- lin GEMM: 64x64 tile, BK=64, panel LDS
__global__ __launch_bounds__(256) void k_gemm_lin(const _Float16* __restrict__ A,
        const _Float16* __restrict__ Bt, const float* __restrict__ bias,
        float* __restrict__ y) {
    __shared__ _Float16 As[2 * 64 * 32];
    __shared__ _Float16 Bs[2 * 64 * 32];
    const int tid = threadIdx.x;
    const int w = tid >> 6, lane = tid & 63;
    const int nn = lane & 15, qd = lane >> 4;
    const int wm = (w & 1) << 5, wn = (w >> 1) << 5;
    const int m0 = blockIdx.x << 6, n0 = blockIdx.y << 6;
    const int l2r = lane >> 2, l2c = (lane & 3) << 3;
    const _Float16* Ag = A + (size_t)(m0 + (w << 4) + l2r) * 512 + l2c;
    const _Float16* Bg = Bt + (size_t)(n0 + (w << 4) + l2r) * 512 + l2c;
    _Float16* Al = As + (w << 9);
    _Float16* Bl = Bs + (w << 9);
    floatx4 acc[2][2] = {};
    for (int k0 = 0; k0 < 512; k0 += 64) {
        __syncthreads();
        #pragma unroll
        for (int p = 0; p < 2; p++) {
            async16(Ag + k0 + (p << 5), Al + (p << 11));
            async16(Bg + k0 + (p << 5), Bl + (p << 11));
        }
        __syncthreads();
        #pragma unroll
        for (int ks = 0; ks < 2; ks++) {
            half8 af[2], bf[2];
            #pragma unroll
            for (int t = 0; t < 2; t++) {
                af[t] = *(const half8*)&As[(ks << 11) + ((wm + (t << 4) + nn) << 5) + (qd << 3)];
                bf[t] = *(const half8*)&Bs[(ks << 11) + ((wn + (t << 4) + nn) << 5) + (qd << 3)];
            }
            #pragma unroll
            for (int ti = 0; ti < 2; ti++)
                #pragma unroll
                for (int tj = 0; tj < 2; tj++)
                    acc[ti][tj] = __builtin_amdgcn_mfma_f32_16x16x32_f16(
                            af[ti], bf[tj], acc[ti][tj], 0, 0, 0);
        }
    }
    float bv2[2];
    #pragma unroll
    for (int tj = 0; tj < 2; tj++) bv2[tj] = bias[n0 + wn + (tj << 4) + nn];
    #pragma unroll
    for (int ti = 0; ti < 2; ti++) {
        int rg = m0 + wm + (ti << 4) + (qd << 2);
        #pragma unroll
        for (int tj = 0; tj < 2; tj++) {
            int colg = n0 + wn + (tj << 4) + nn;
            float* op = y + (size_t)rg * 512 + colg;
            #pragma unroll
            for (int r = 0; r < 4; r++)
                op[(size_t)r * 512] = acc[ti][tj][r] + bv2[tj];
        }
    }
}

// ---------------------------------------------------------------- MFMA causal rel-pos attention (f16)
// DIAGNOSTIC: 3 identical passes; output = (1/3) * sum of per-pass normalized O.
// Numerically identical within ~2 ulp; exposes per-dispatch cost = (dur - base)/2.
__global__ __launch_bounds__(256, 4) void k_attn_mfma(const _Float16* __restrict__ q,
        const _Float16* __restrict__ k, const _Float16* __restrict__ v,
        const _Float16* __restrict__ Er, _Float16* __restrict__ aout) {
    __shared__ _Float16 Ks[256][20];
    __shared__ _Float16 Vts[16][268];
    __shared__ float Rel[4][16][80];
    const int tid = threadIdx.x;
    const int wid = tid >> 6, lane = tid & 63;
    const int nn = lane & 15, a4 = (lane >> 4) << 2;
    const int b_ = blockIdx.x >> 5, h_ = blockIdx.x & 31;
    const int y = blockIdx.y;
    const int t_ = tid >> 2, c4 = (tid & 3) << 2;
    const int r0p[2] = {64 * y, 64 * (15 - y)};
    const int R = r0p[1] + 64;

    half4 qf[2];
    floatx4 Oacc[2] = {};
    #pragma unroll
    for (int ph = 0; ph < 2; ph++) {
        int s0w = r0p[ph] + (wid << 4);
        qf[ph] = *(const half4*)(q + ((size_t)(b_ * SEQ + s0w + nn)) * DIM + h_ * DHD + a4);
    }

    #pragma unroll 1
    for (int pass = 0; pass < 3; pass++) {
        floatx4 O[2];
        float m[2], lsum[2];
        #pragma unroll
        for (int ph = 0; ph < 2; ph++) {
            O[ph] = (floatx4){0.f, 0.f, 0.f, 0.f};
            m[ph] = NEGF;
            lsum[ph] = 0.f;
        }
        for (int part = 0; part < 4; part++) {
            const int p0 = part << 8;
            if (p0 >= R) break;
            const int pend = (R < p0 + 256) ? R : (p0 + 256);
            __syncthreads();
            const int ng = (pend - p0) >> 6;
            for (int g = 0; g < ng; g++) {             // stage K + V^T rows [p0, pend)
                int rl = (g << 6) + t_;
                size_t gb = ((size_t)(b_ * SEQ + p0 + rl)) * DIM + h_ * DHD + c4;
                *(half4*)&Ks[rl][c4] = *(const half4*)(k + gb);
                half4 vv4 = *(const half4*)(v + gb);
                Vts[c4 + 0][rl] = vv4.x;
                Vts[c4 + 1][rl] = vv4.y;
                Vts[c4 + 2][rl] = vv4.z;
                Vts[c4 + 3][rl] = vv4.w;
            }
            __syncthreads();
            #pragma unroll
            for (int ph = 0; ph < 2; ph++) {
                const int r0 = r0p[ph];
                const int s0w = r0 + (wid << 4);
                const int hi = (r0 + 64 < pend) ? (r0 + 64) : pend;
                for (int ct = p0; ct < hi; ct += 64) {
                    const int ctl = ct - p0;
                    const int jbw = 1008 - s0w + ct;
                    #pragma unroll
                    for (int jt = 0; jt < 5; jt++) {
                        int j = jbw + (jt << 4) + nn;
                        j = (j < SEQ - 1) ? j : (SEQ - 1);
                        half4 ef = *(const half4*)(Er + (size_t)j * DHD + a4);
                        floatx4 racc = {0.f, 0.f, 0.f, 0.f};
                        racc = __builtin_amdgcn_mfma_f32_16x16x16f16(ef, qf[ph], racc, 0, 0, 0);
                        *(floatx4*)&Rel[wid][nn][(jt << 4) + a4] = racc;
                    }
                    float st[4][4];
                    const bool diag = (ct == r0);
                    #pragma unroll
                    for (int tt = 0; tt < 4; tt++) {
                        half4 kf = *(const half4*)&Ks[ctl + (tt << 4) + nn][a4];
                        floatx4 sacc = {0.f, 0.f, 0.f, 0.f};
                        sacc = __builtin_amdgcn_mfma_f32_16x16x16f16(kf, qf[ph], sacc, 0, 0, 0);
                        const float* rp = &Rel[wid][nn][15 - nn + (tt << 4) + a4];
                        #pragma unroll
                        for (int r = 0; r < 4; r++) {
                            int tl = (tt << 4) + a4 + r;
                            float sv = sacc[r] + rp[r];
                            if (diag && (tl > (wid << 4) + nn)) sv = NEGF;
                            st[tt][r] = sv;
                        }
                    }
                    float cmax = NEGF;
                    #pragma unroll
                    for (int tt = 0; tt < 4; tt++)
                        #pragma unroll
                        for (int r = 0; r < 4; r++) cmax = fmaxf(cmax, st[tt][r]);
                    cmax = fmaxf(cmax, __shfl_xor(cmax, 16));
                    cmax = fmaxf(cmax, __shfl_xor(cmax, 32));
                    float mnew = fmaxf(m[ph], cmax);
                    float alpha = exp2f(m[ph] - mnew);
                    m[ph] = mnew;
                    float csum = 0.f;
                    half4 pf[4];
                    #pragma unroll
                    for (int tt = 0; tt < 4; tt++) {
                        float p0e = exp2f(st[tt][0] - mnew);
                        float p1e = exp2f(st[tt][1] - mnew);
                        float p2e = exp2f(st[tt][2] - mnew);
                        float p3e = exp2f(st[tt][3] - mnew);
                        csum += (p0e + p1e) + (p2e + p3e);
                        half4 ph4 = {(_Float16)p0e, (_Float16)p1e, (_Float16)p2e, (_Float16)p3e};
                        pf[tt] = ph4;
                    }
                    lsum[ph] = lsum[ph] * alpha + csum;
                    O[ph][0] *= alpha; O[ph][1] *= alpha; O[ph][2] *= alpha; O[ph][3] *= alpha;
                    #pragma unroll
                    for (int tt = 0; tt < 4; tt++) {
                        half4 vf = *(const half4*)&Vts[nn][ctl + (tt << 4) + a4];
                        O[ph] = __builtin_amdgcn_mfma_f32_16x16x16f16(vf, pf[tt], O[ph], 0, 0, 0);
                    }
                }
            }
        }
        #pragma unroll
        for (int ph = 0; ph < 2; ph++) {
            float lt = lsum[ph];
            lt += __shfl_xor(lt, 16);
            lt += __shfl_xor(lt, 32);
            float linv = 1.0f / lt;
            Oacc[ph][0] += O[ph][0] * linv;
            Oacc[ph][1] += O[ph][1] * linv;
            Oacc[ph][2] += O[ph][2] * linv;
            Oacc[ph][3] += O[ph][3] * linv;
        }
    }
    #pragma unroll
    for (int ph = 0; ph < 2; ph++) {
        const float third = 1.0f / 3.0f;
        int s0w = r0p[ph] + (wid << 4);
        half4 ov = { (_Float16)(Oacc[ph][0] * third), (_Float16)(Oacc[ph][1] * third),
                     (_Float16)(Oacc[ph][2] * third), (_Float16)(Oacc[ph][3] * third) };
        *(half4*)(aout + ((size_t)(b_ * SEQ + s0w + nn)) * DIM + h_ * DHD + a4) = ov;
    }
}

// ---------------------------------------------------------------- h += gelu(LN(y)): one wave per row
__global__ __launch_bounds__(256) void k_ln_gelu_res(const float* __restrict__ y,
        const float* __restrict__ gam, const float* __restrict__ bet,
        float* __restrict__ h, _Float16* __restrict__ hf) {
    int row = (blockIdx.x << 2) + (threadIdx.x >> 6);
    int lane = threadIdx.x & 63;
    const float* yr = y + (size_t)row * DIM + (lane << 3);
    float4 v0 = *(const float4*)(yr);
    float4 v1 = *(const float4*)(yr + 4);
    float sum = (v0.x + v0.y) + (v0.z + v0.w) + (v1.x + v1.y) + (v1.z + v1.w);
    float sq = v0.x*v0.x + v0.y*v0.y + v0.z*v0.z + v0.w*v0.w
             + v1.x*v1.x + v1.y*v1.y + v1.z*v1.z + v1.w*v1.w;
    #pragma unroll
    for (int off = 32; off > 0; off >>= 1) {
        sum += __shfl_xor(sum, off);
        sq  += __shfl_xor(sq, off);
    }
    float mu = sum * (1.0f / DIM);
    float var = sq * (1.0f / DIM) - mu * mu;
    float rs = rsqrtf(var + LN_EPS);
    float4 g0 = *(const float4*)(gam + (lane << 3));
    float4 g1 = *(const float4*)(gam + (lane << 3) + 4);
    float4 b0 = *(const float4*)(bet + (lane << 3));
    float4 b1 = *(const float4*)(bet + (lane << 3) + 4);
    float* hr = h + (size_t)row * DIM + (lane << 3);
    float4 h0 = *(const float4*)(hr);
    float4 h1 = *(const float4*)(hr + 4);
    float o[8];
    o[0] = h0.x + gelu_exact((v0.x - mu) * rs * g0.x + b0.x);
    o[1] = h0.y + gelu_exact((v0.y - mu) * rs * g0.y + b0.y);
    o[2] = h0.z + gelu_exact((v0.z - mu) * rs * g0.z + b0.z);
    o[3] = h0.w + gelu_exact((v0.w - mu) * rs * g0.w + b0.w);
    o[4] = h1.x + gelu_exact((v1.x - mu) * rs * g1.x + b1.x);
    o[5] = h1.y + gelu_exact((v1.y - mu) * rs * g1.y + b1.y);
    o[6] = h1.z + gelu_exact((v1.z - mu) * rs * g1.z + b1.z);
    o[7] = h1.w + gelu_exact((v1.w - mu) * rs * g1.w + b1.w);
    *(float4*)(hr)     = make_float4(o[0], o[1], o[2], o[3]);
    *(float4*)(hr + 4) = make_float4(o[4], o[5], o[6], o[7]);
    half8 oh = {(_Float16)o[0], (_Float16)o[1], (_Float16)o[2], (_Float16)o[3],
                (_Float16)o[4], (_Float16)o[5], (_Float16)o[6], (_Float16)o[7]};
    *(half8*)(hf + (size_t)row * DIM + (lane << 3)) = oh;
}

// ---------------------------------------------------------------- final reduction, parallel
__global__ __launch_bounds__(256) void k_colsum1(const float* __restrict__ h,
        float* __restrict__ pa) {
    int bt = blockIdx.x;                   // 256 blocks, 8 rows each
    int base = bt << 3;
    int tid = threadIdx.x;
    #pragma unroll
    for (int half = 0; half < 2; half++) {
        int d = (half << 8) + tid;
        float acc = 0.f;
        #pragma unroll
        for (int i = 0; i < 8; i++)
            acc += h[(size_t)(base + i) * DIM + d];
        pa[(size_t)bt * DIM + d] = acc;
    }
}

__global__ __launch_bounds__(256) void k_colsum2(const float* __restrict__ pa,
        float* __restrict__ pb) {
    __shared__ float red[4][64];
    int b = blockIdx.x, dt = blockIdx.y;   // grid (2,8)
    int tid = threadIdx.x;
    int c = tid & 63, ig = tid >> 6;
    int d = (dt << 6) + c;
    float s = 0.f;
    for (int i = ig; i < 128; i += 4)
        s += pa[(size_t)(b * 128 + i) * DIM + d];
    red[ig][c] = s;
    __syncthreads();
    if (ig == 0)
        pb[(size_t)b * DIM + d] = red[0][c] + red[1][c] + red[2][c] + red[3][c];
}

__global__ __launch_bounds__(256) void k_final(const float* __restrict__ pb,
        const float* __restrict__ Wout, float* __restrict__ out) {
    __shared__ float red[4][2];
    int tid = threadIdx.x;
    float acc0 = 0.f, acc1 = 0.f;
    #pragma unroll
    for (int half = 0; half < 2; half++) {
        int d = (half << 8) + tid;
        float w = Wout[d];
        acc0 += pb[d] * w;
        acc1 += pb[DIM + d] * w;
    }
    #pragma unroll
    for (int off = 32; off > 0; off >>= 1) {
        acc0 += __shfl_down(acc0, off);
        acc1 += __shfl_down(acc1, off);
    }
    if ((tid & 63) == 0) { red[tid >> 6][0] = acc0; red[tid >> 6][1] = acc1; }
    __syncthreads();
    if (tid == 0) {
        out[0] = red[0][0] + red[1][0] + red[2][0] + red[3][0];
        out[1] = red[0][1] + red[1][1] + red[2][1] + red[3][1];
    }
}

extern "C" void kernel_launch(void* const* d_in, const int* in_sizes, int n_in,
                              void* d_out, int out_size, void* d_ws, size_t ws_size,
                              hipStream_t stream) {
    const float* x    = (const float*)d_in[0];
    const float* Wi   = (const float*)d_in[1];
    const float* bi   = (const float*)d_in[2];
    const float* Wq   = (const float*)d_in[3];
    const float* bq   = (const float*)d_in[4];
    const float* Wk   = (const float*)d_in[5];
    const float* bk   = (const float*)d_in[6];
    const float* Wv   = (const float*)d_in[7];
    const float* bv   = (const float*)d_in[8];
    const float* Er   = (const float*)d_in[9];
    const float* Wlin = (const float*)d_in[10];
    const float* blin = (const float*)d_in[11];
    const float* lng  = (const float*)d_in[12];
    const float* lnb  = (const float*)d_in[13];
    const float* Wout = (const float*)d_in[14];
    float* out = (float*)d_out;

    float* ws = (float*)d_ws;
    const size_t N1 = 1048576;                       // B*S*D
    float*     h     = ws;                           // [0, 1N)
    _Float16*  hf    = (_Float16*)(ws + N1);         // [1N, 1.5N)
    _Float16*  qh    = (_Float16*)(ws + N1 + N1/2);  // [1.5N, 3N): q,k,v f16
    _Float16*  ah    = (_Float16*)(ws + 3 * N1);     // [3N, 3.5N)
    float*     y     = ws + 3 * N1 + N1/2;           // [3.5N, 4.5N)
    _Float16*  Wqkvt = (_Float16*)(ws + 4 * N1 + N1/2);  // [4.5N, 6N)
    _Float16*  Wlint = (_Float16*)(ws + 6 * N1);         // [6N, 6.5N)
    float*     bqkv  = ws + 6 * N1 + N1/2;               // 6144 floats
    _Float16*  Erh   = (_Float16*)(ws + 6 * N1 + N1/2 + 8192);  // 65536 f16
    float*     pa    = ws + 6 * N1 + N1/2 + 8192 + 32768;       // 131072 floats
    float*     pb    = pa + 131072;                              // 1024 floats

    k_prep_all<<<dim3(2328), dim3(256), 0, stream>>>(Wq, Wk, Wv, Wlin, bq, bk, bv,
            Er, x, Wi, bi, Wqkvt, Wlint, bqkv, Erh, h, hf);
    for (int l = 0; l < NL; l++) {
        k_gemm_qkv<<<dim3(16, 16), dim3(256), 0, stream>>>(
                hf, Wqkvt + (size_t)l * 786432, bqkv + l * 1536, qh);
        k_attn_mfma<<<dim3(NB * NH, 8), dim3(256), 0, stream>>>(
                qh, qh + 1048576, qh + 2097152, Erh + (size_t)l * 16384, ah);
        k_gemm_lin<<<dim3(32, 8), dim3(256), 0, stream>>>(
                ah, Wlint + (size_t)l * 262144, blin + l * 512, y);
        k_ln_gelu_res<<<dim3(512), dim3(256), 0, stream>>>(
                y, lng + l * 512, lnb + l * 512, h, hf);
    }
    k_colsum1<<<dim3(256), dim3(256), 0, stream>>>(h, pa);
    k_colsum2<<<dim3(2, 8), dim3(256), 0, stream>>>(pa, pb);
    k_final<<<dim3(1), dim3(256), 0, stream>>>(pb, Wout, out);
}

// Round 11
// 300.837 us; speedup vs baseline: 1.7360x; 1.7360x over previous
//
#include <hip/hip_runtime.h>
#include <math.h>

#define NL 4
#define DIM 512
#define NH 32
#define DHD 16
#define SEQ 1024
#define NB 2
#define LN_EPS 1e-5f
#define NEGF (-1e30f)
#define QSC 0.36067376022224085f   // 0.25 * log2(e), folded into Wq/bq

typedef _Float16 half4 __attribute__((ext_vector_type(4)));
typedef _Float16 half8 __attribute__((ext_vector_type(8)));
typedef float floatx4 __attribute__((ext_vector_type(4)));

__device__ __forceinline__ float gelu_exact(float x) {
    return 0.5f * x * (1.0f + erff(x * 0.70710678118654752f));
}

// async global->LDS, 16 B per lane; LDS base wave-uniform, lane i lands at base + i*16
__device__ __forceinline__ void async16(const void* g, void* l) {
    __builtin_amdgcn_global_load_lds(
        (const __attribute__((address_space(1))) void*)g,
        (__attribute__((address_space(3))) void*)l, 16, 0, 0);
}

// ---------------------------------------------------------------- fused prep: weights^T f16 + biases + Er f16 + init
__global__ __launch_bounds__(256) void k_prep_all(const float* __restrict__ Wq,
        const float* __restrict__ Wk, const float* __restrict__ Wv,
        const float* __restrict__ Wlin, const float* __restrict__ bq,
        const float* __restrict__ bk, const float* __restrict__ bv,
        const float* __restrict__ Er, const float* __restrict__ x,
        const float* __restrict__ Wi, const float* __restrict__ bi,
        _Float16* __restrict__ Wqkvt, _Float16* __restrict__ Wlint,
        float* __restrict__ bqkv, _Float16* __restrict__ Erh,
        float* __restrict__ h, _Float16* __restrict__ hf) {
    __shared__ _Float16 lt[64][72];
    const int u = blockIdx.x;
    const int tid = threadIdx.x;
    if (u < 1024) {                       // ---- weight transpose-convert
        const int kx = u & 7, ny = (u >> 3) & 7, mz = u >> 6;
        const int l = mz >> 2, which = mz & 3;
        const float* src = (which == 0) ? Wq : (which == 1) ? Wk : (which == 2) ? Wv : Wlin;
        src += (size_t)l * 262144;
        const float scale = (which == 0) ? QSC : 1.0f;
        _Float16* dst = (which < 3) ? (Wqkvt + (size_t)l * 786432 + (size_t)which * 262144)
                                    : (Wlint + (size_t)l * 262144);
        const int k0 = kx << 6, n0 = ny << 6;
        #pragma unroll
        for (int p = 0; p < 4; p++) {
            int kl = (p << 4) + (tid >> 4);
            int n4 = (tid & 15) << 2;
            float4 wv = *(const float4*)(src + (size_t)(k0 + kl) * 512 + n0 + n4);
            lt[n4 + 0][kl] = (_Float16)(wv.x * scale);
            lt[n4 + 1][kl] = (_Float16)(wv.y * scale);
            lt[n4 + 2][kl] = (_Float16)(wv.z * scale);
            lt[n4 + 3][kl] = (_Float16)(wv.w * scale);
        }
        __syncthreads();
        int nl = tid >> 2, k16 = (tid & 3) << 4;
        float4* d4 = (float4*)(dst + (size_t)(n0 + nl) * 512 + k0 + k16);
        const float4* s4 = (const float4*)&lt[nl][k16];
        d4[0] = s4[0];
        d4[1] = s4[1];
    } else if (u < 2048) {                // ---- init: h = gelu(x*Wi + bi), + f16 copy
        int idx0 = ((u - 1024) << 10) + (tid << 2);
        int d = idx0 & 511, bs = idx0 >> 9;
        float xs = x[bs];
        float4 wv = *(const float4*)(Wi + d);
        float4 bv = *(const float4*)(bi + d);
        float4 r;
        r.x = gelu_exact(xs * wv.x + bv.x);
        r.y = gelu_exact(xs * wv.y + bv.y);
        r.z = gelu_exact(xs * wv.z + bv.z);
        r.w = gelu_exact(xs * wv.w + bv.w);
        *(float4*)(h + idx0) = r;
        half4 rh = {(_Float16)r.x, (_Float16)r.y, (_Float16)r.z, (_Float16)r.w};
        *(half4*)(hf + idx0) = rh;
    } else {                              // ---- biases (bq scaled) + Er f16
        int idx = ((u - 2048) << 8) + tid;
        if (idx < NL * 1536) {
            int l = idx / 1536, j = idx % 1536;
            int which = j >> 9, jj = j & 511;
            float val = (which == 0) ? bq[l * 512 + jj] * QSC
                      : (which == 1) ? bk[l * 512 + jj] : bv[l * 512 + jj];
            bqkv[idx] = val;
        }
        int e = idx - NL * 1536;
        if (e >= 0 && e < NL * SEQ * DHD) Erh[e] = (_Float16)Er[e];
    }
}

// ---------------------------------------------------------------- qkv GEMM: 128x96 tile, BK=64, async panels
__global__ __launch_bounds__(256) void k_gemm_qkv(const _Float16* __restrict__ A,
        const _Float16* __restrict__ Bt, const float* __restrict__ bias,
        _Float16* __restrict__ o16) {
    __shared__ _Float16 As[2][128][32];   // 16 KB
    __shared__ _Float16 Bs[2][96][32];    // 12 KB
    const int tid = threadIdx.x;
    const int w = tid >> 6, lane = tid & 63;
    const int nn = lane & 15, qd = lane >> 4;
    const int wm = (w & 1) << 6;          // 0 / 64
    const int wn = (w >> 1) * 48;         // 0 / 48
    const int m0 = blockIdx.x << 7;
    const int n0 = blockIdx.y * 96;
    const int srow = lane >> 2, scol = (lane & 3) << 3;
    floatx4 acc[4][3] = {};
    for (int k0 = 0; k0 < 512; k0 += 64) {
        __syncthreads();
        #pragma unroll
        for (int p = 0; p < 2; p++) {
            #pragma unroll
            for (int hh = 0; hh < 2; hh++)
                async16(A + (size_t)(m0 + (hh << 6) + (w << 4) + srow) * 512
                          + k0 + (p << 5) + scol,
                        &As[p][(hh << 6) + (w << 4)][0]);
            async16(Bt + (size_t)(n0 + (w << 4) + srow) * 512 + k0 + (p << 5) + scol,
                    &Bs[p][(w << 4)][0]);
            if (w < 2)
                async16(Bt + (size_t)(n0 + 64 + (w << 4) + srow) * 512
                           + k0 + (p << 5) + scol,
                        &Bs[p][64 + (w << 4)][0]);
        }
        __syncthreads();
        #pragma unroll
        for (int ks = 0; ks < 2; ks++) {
            half8 af[4], bf[3];
            #pragma unroll
            for (int t = 0; t < 4; t++)
                af[t] = *(const half8*)&As[ks][wm + (t << 4) + nn][qd << 3];
            #pragma unroll
            for (int t = 0; t < 3; t++)
                bf[t] = *(const half8*)&Bs[ks][wn + (t << 4) + nn][qd << 3];
            #pragma unroll
            for (int ti = 0; ti < 4; ti++)
                #pragma unroll
                for (int tj = 0; tj < 3; tj++)
                    acc[ti][tj] = __builtin_amdgcn_mfma_f32_16x16x32_f16(
                            af[ti], bf[tj], acc[ti][tj], 0, 0, 0);
        }
    }
    float bv3[3];
    #pragma unroll
    for (int tj = 0; tj < 3; tj++) bv3[tj] = bias[n0 + wn + (tj << 4) + nn];
    #pragma unroll
    for (int ti = 0; ti < 4; ti++) {
        int rg = m0 + wm + (ti << 4) + (qd << 2);
        #pragma unroll
        for (int tj = 0; tj < 3; tj++) {
            int colg = n0 + wn + (tj << 4) + nn;
            int which = colg >> 9, ci = colg & 511;
            _Float16* op = o16 + (size_t)which * 1048576 + (size_t)rg * 512 + ci;
            #pragma unroll
            for (int r = 0; r < 4; r++)
                op[(size_t)r * 512] = (_Float16)(acc[ti][tj][r] + bv3[tj]);
        }
    }
}

// ---------------------------------------------------------------- lin GEMM: 64x64 tile, BK=64, panel LDS
__global__ __launch_bounds__(256) void k_gemm_lin(const _Float16* __restrict__ A,
        const _Float16* __restrict__ Bt, const float* __restrict__ bias,
        float* __restrict__ y) {
    __shared__ _Float16 As[2 * 64 * 32];
    __shared__ _Float16 Bs[2 * 64 * 32];
    const int tid = threadIdx.x;
    const int w = tid >> 6, lane = tid & 63;
    const int nn = lane & 15, qd = lane >> 4;
    const int wm = (w & 1) << 5, wn = (w >> 1) << 5;
    const int m0 = blockIdx.x << 6, n0 = blockIdx.y << 6;
    const int l2r = lane >> 2, l2c = (lane & 3) << 3;
    const _Float16* Ag = A + (size_t)(m0 + (w << 4) + l2r) * 512 + l2c;
    const _Float16* Bg = Bt + (size_t)(n0 + (w << 4) + l2r) * 512 + l2c;
    _Float16* Al = As + (w << 9);
    _Float16* Bl = Bs + (w << 9);
    floatx4 acc[2][2] = {};
    for (int k0 = 0; k0 < 512; k0 += 64) {
        __syncthreads();
        #pragma unroll
        for (int p = 0; p < 2; p++) {
            async16(Ag + k0 + (p << 5), Al + (p << 11));
            async16(Bg + k0 + (p << 5), Bl + (p << 11));
        }
        __syncthreads();
        #pragma unroll
        for (int ks = 0; ks < 2; ks++) {
            half8 af[2], bf[2];
            #pragma unroll
            for (int t = 0; t < 2; t++) {
                af[t] = *(const half8*)&As[(ks << 11) + ((wm + (t << 4) + nn) << 5) + (qd << 3)];
                bf[t] = *(const half8*)&Bs[(ks << 11) + ((wn + (t << 4) + nn) << 5) + (qd << 3)];
            }
            #pragma unroll
            for (int ti = 0; ti < 2; ti++)
                #pragma unroll
                for (int tj = 0; tj < 2; tj++)
                    acc[ti][tj] = __builtin_amdgcn_mfma_f32_16x16x32_f16(
                            af[ti], bf[tj], acc[ti][tj], 0, 0, 0);
        }
    }
    float bv2[2];
    #pragma unroll
    for (int tj = 0; tj < 2; tj++) bv2[tj] = bias[n0 + wn + (tj << 4) + nn];
    #pragma unroll
    for (int ti = 0; ti < 2; ti++) {
        int rg = m0 + wm + (ti << 4) + (qd << 2);
        #pragma unroll
        for (int tj = 0; tj < 2; tj++) {
            int colg = n0 + wn + (tj << 4) + nn;
            float* op = y + (size_t)rg * 512 + colg;
            #pragma unroll
            for (int r = 0; r < 4; r++)
                op[(size_t)r * 512] = acc[ti][tj][r] + bv2[tj];
        }
    }
}

// ---------------------------------------------------------------- MFMA causal rel-pos attention (f16)
// Block = 512 thr (8 waves), grid (B*H, 8). Paired phases r0 = {64y, 64(15-y)}.
// Waves 0-3 (half=0) process EVEN global chunks, waves 4-7 (half=1) ODD chunks;
// staging shared by all 8 waves. End: merge the two online-softmax states via LDS.
// Rel stride 84: b128 writes 2-way (bank 20nn+4qd), b32 reads distinct (19nn).
__global__ __launch_bounds__(512) void k_attn_mfma(const _Float16* __restrict__ q,
        const _Float16* __restrict__ k, const _Float16* __restrict__ v,
        const _Float16* __restrict__ Er, _Float16* __restrict__ aout) {
    __shared__ _Float16 Ks[256][20];    // 10 KB
    __shared__ _Float16 Vts[16][268];   // 8.4 KB
    __shared__ float Rel[8][16][84];    // 43 KB; merge buffer reuses this space
    const int tid = threadIdx.x;
    const int w = tid >> 6, lane = tid & 63;
    const int wg = w & 3, half = w >> 2;
    const int nn = lane & 15, a4 = (lane >> 4) << 2;
    const int b_ = blockIdx.x >> 5, h_ = blockIdx.x & 31;
    const int y = blockIdx.y;
    const int r0p[2] = {64 * y, 64 * (15 - y)};
    const int R = r0p[1] + 64;

    half4 qf[2];
    floatx4 O[2];
    float m[2], lsum[2];
    #pragma unroll
    for (int ph = 0; ph < 2; ph++) {
        int s0w = r0p[ph] + (wg << 4);
        qf[ph] = *(const half4*)(q + ((size_t)(b_ * SEQ + s0w + nn)) * DIM + h_ * DHD + a4);
        O[ph] = (floatx4){0.f, 0.f, 0.f, 0.f};
        m[ph] = NEGF;
        lsum[ph] = 0.f;
    }

    for (int part = 0; part < 4; part++) {
        const int p0 = part << 8;
        if (p0 >= R) break;
        const int pend = (R < p0 + 256) ? R : (p0 + 256);
        __syncthreads();
        {   // stage K + V^T rows [p0, pend): 512 threads cover 128 rows/iter
            int rl0 = tid >> 2, c4 = (tid & 3) << 2;
            for (int g = 0; g < pend - p0; g += 128) {
                int rl = g + rl0;
                if (rl < pend - p0) {
                    size_t gb = ((size_t)(b_ * SEQ + p0 + rl)) * DIM + h_ * DHD + c4;
                    *(half4*)&Ks[rl][c4] = *(const half4*)(k + gb);
                    half4 vv4 = *(const half4*)(v + gb);
                    Vts[c4 + 0][rl] = vv4.x;
                    Vts[c4 + 1][rl] = vv4.y;
                    Vts[c4 + 2][rl] = vv4.z;
                    Vts[c4 + 3][rl] = vv4.w;
                }
            }
        }
        __syncthreads();
        #pragma unroll
        for (int ph = 0; ph < 2; ph++) {
            const int r0 = r0p[ph];
            const int s0w = r0 + (wg << 4);
            const int hi = (r0 + 64 < pend) ? (r0 + 64) : pend;
            for (int ct = p0; ct < hi; ct += 64) {
                if (((ct >> 6) & 1) != half) continue;     // chunk-parity split
                const int ctl = ct - p0;
                // QEr^T j-tiles -> Rel (clamped rows masked later)
                const int jbw = 1008 - s0w + ct;
                #pragma unroll
                for (int jt = 0; jt < 5; jt++) {
                    int j = jbw + (jt << 4) + nn;
                    j = (j < SEQ - 1) ? j : (SEQ - 1);
                    half4 ef = *(const half4*)(Er + (size_t)j * DHD + a4);
                    floatx4 racc = {0.f, 0.f, 0.f, 0.f};
                    racc = __builtin_amdgcn_mfma_f32_16x16x16f16(ef, qf[ph], racc, 0, 0, 0);
                    *(floatx4*)&Rel[w][nn][(jt << 4) + a4] = racc;
                }
                // St = K·Q^T + Srel + causal mask
                float st[4][4];
                const bool diag = (ct == r0);
                #pragma unroll
                for (int tt = 0; tt < 4; tt++) {
                    half4 kf = *(const half4*)&Ks[ctl + (tt << 4) + nn][a4];
                    floatx4 sacc = {0.f, 0.f, 0.f, 0.f};
                    sacc = __builtin_amdgcn_mfma_f32_16x16x16f16(kf, qf[ph], sacc, 0, 0, 0);
                    const float* rp = &Rel[w][nn][15 - nn + (tt << 4) + a4];
                    #pragma unroll
                    for (int r = 0; r < 4; r++) {
                        int tl = (tt << 4) + a4 + r;
                        float sv = sacc[r] + rp[r];
                        if (diag && (tl > (wg << 4) + nn)) sv = NEGF;
                        st[tt][r] = sv;
                    }
                }
                // online softmax (exp2 domain); m reduced over quads, l per-lane
                float cmax = NEGF;
                #pragma unroll
                for (int tt = 0; tt < 4; tt++)
                    #pragma unroll
                    for (int r = 0; r < 4; r++) cmax = fmaxf(cmax, st[tt][r]);
                cmax = fmaxf(cmax, __shfl_xor(cmax, 16));
                cmax = fmaxf(cmax, __shfl_xor(cmax, 32));
                float mnew = fmaxf(m[ph], cmax);
                float alpha = exp2f(m[ph] - mnew);
                m[ph] = mnew;
                float csum = 0.f;
                half4 pf[4];
                #pragma unroll
                for (int tt = 0; tt < 4; tt++) {
                    float p0e = exp2f(st[tt][0] - mnew);
                    float p1e = exp2f(st[tt][1] - mnew);
                    float p2e = exp2f(st[tt][2] - mnew);
                    float p3e = exp2f(st[tt][3] - mnew);
                    csum += (p0e + p1e) + (p2e + p3e);
                    half4 ph4 = {(_Float16)p0e, (_Float16)p1e, (_Float16)p2e, (_Float16)p3e};
                    pf[tt] = ph4;
                }
                lsum[ph] = lsum[ph] * alpha + csum;
                O[ph][0] *= alpha; O[ph][1] *= alpha; O[ph][2] *= alpha; O[ph][3] *= alpha;
                #pragma unroll
                for (int tt = 0; tt < 4; tt++) {
                    half4 vf = *(const half4*)&Vts[nn][ctl + (tt << 4) + a4];
                    O[ph] = __builtin_amdgcn_mfma_f32_16x16x16f16(vf, pf[tt], O[ph], 0, 0, 0);
                }
            }
        }
    }
    // ---- merge half=1 state into half=0, then finalize (reuse Rel as scratch)
    float* mb = (float*)Rel;
    __syncthreads();
    if (half == 1) {
        #pragma unroll
        for (int ph = 0; ph < 2; ph++) {
            int base = (((wg << 1) + ph) << 6) + lane;
            mb[base]        = O[ph][0];
            mb[base + 1024] = O[ph][1];
            mb[base + 2048] = O[ph][2];
            mb[base + 3072] = O[ph][3];
            mb[base + 4096] = m[ph];
            mb[base + 5120] = lsum[ph];
        }
    }
    __syncthreads();
    if (half == 0) {
        #pragma unroll
        for (int ph = 0; ph < 2; ph++) {
            int base = (((wg << 1) + ph) << 6) + lane;
            float m1 = mb[base + 4096];
            float l1 = mb[base + 5120];
            float mm = fmaxf(m[ph], m1);             // m[ph] finite: half0 owns chunk 0
            float a0 = exp2f(m[ph] - mm);
            float a1 = exp2f(m1 - mm);
            float lt = lsum[ph] * a0 + l1 * a1;
            lt += __shfl_xor(lt, 16);
            lt += __shfl_xor(lt, 32);
            float linv = 1.0f / lt;
            float o0 = (O[ph][0] * a0 + mb[base]        * a1) * linv;
            float o1 = (O[ph][1] * a0 + mb[base + 1024] * a1) * linv;
            float o2 = (O[ph][2] * a0 + mb[base + 2048] * a1) * linv;
            float o3 = (O[ph][3] * a0 + mb[base + 3072] * a1) * linv;
            int s0w = r0p[ph] + (wg << 4);
            half4 ov = {(_Float16)o0, (_Float16)o1, (_Float16)o2, (_Float16)o3};
            *(half4*)(aout + ((size_t)(b_ * SEQ + s0w + nn)) * DIM + h_ * DHD + a4) = ov;
        }
    }
}

// ---------------------------------------------------------------- h += gelu(LN(y)): one wave per row
__global__ __launch_bounds__(256) void k_ln_gelu_res(const float* __restrict__ y,
        const float* __restrict__ gam, const float* __restrict__ bet,
        float* __restrict__ h, _Float16* __restrict__ hf) {
    int row = (blockIdx.x << 2) + (threadIdx.x >> 6);
    int lane = threadIdx.x & 63;
    const float* yr = y + (size_t)row * DIM + (lane << 3);
    float4 v0 = *(const float4*)(yr);
    float4 v1 = *(const float4*)(yr + 4);
    float sum = (v0.x + v0.y) + (v0.z + v0.w) + (v1.x + v1.y) + (v1.z + v1.w);
    float sq = v0.x*v0.x + v0.y*v0.y + v0.z*v0.z + v0.w*v0.w
             + v1.x*v1.x + v1.y*v1.y + v1.z*v1.z + v1.w*v1.w;
    #pragma unroll
    for (int off = 32; off > 0; off >>= 1) {
        sum += __shfl_xor(sum, off);
        sq  += __shfl_xor(sq, off);
    }
    float mu = sum * (1.0f / DIM);
    float var = sq * (1.0f / DIM) - mu * mu;
    float rs = rsqrtf(var + LN_EPS);
    float4 g0 = *(const float4*)(gam + (lane << 3));
    float4 g1 = *(const float4*)(gam + (lane << 3) + 4);
    float4 b0 = *(const float4*)(bet + (lane << 3));
    float4 b1 = *(const float4*)(bet + (lane << 3) + 4);
    float* hr = h + (size_t)row * DIM + (lane << 3);
    float4 h0 = *(const float4*)(hr);
    float4 h1 = *(const float4*)(hr + 4);
    float o[8];
    o[0] = h0.x + gelu_exact((v0.x - mu) * rs * g0.x + b0.x);
    o[1] = h0.y + gelu_exact((v0.y - mu) * rs * g0.y + b0.y);
    o[2] = h0.z + gelu_exact((v0.z - mu) * rs * g0.z + b0.z);
    o[3] = h0.w + gelu_exact((v0.w - mu) * rs * g0.w + b0.w);
    o[4] = h1.x + gelu_exact((v1.x - mu) * rs * g1.x + b1.x);
    o[5] = h1.y + gelu_exact((v1.y - mu) * rs * g1.y + b1.y);
    o[6] = h1.z + gelu_exact((v1.z - mu) * rs * g1.z + b1.z);
    o[7] = h1.w + gelu_exact((v1.w - mu) * rs * g1.w + b1.w);
    *(float4*)(hr)     = make_float4(o[0], o[1], o[2], o[3]);
    *(float4*)(hr + 4) = make_float4(o[4], o[5], o[6], o[7]);
    half8 oh = {(_Float16)o[0], (_Float16)o[1], (_Float16)o[2], (_Float16)o[3],
                (_Float16)o[4], (_Float16)o[5], (_Float16)o[6], (_Float16)o[7]};
    *(half8*)(hf + (size_t)row * DIM + (lane << 3)) = oh;
}

// ---------------------------------------------------------------- final reduction, parallel
__global__ __launch_bounds__(256) void k_colsum1(const float* __restrict__ h,
        float* __restrict__ pa) {
    int bt = blockIdx.x;                   // 256 blocks, 8 rows each
    int base = bt << 3;
    int tid = threadIdx.x;
    #pragma unroll
    for (int half = 0; half < 2; half++) {
        int d = (half << 8) + tid;
        float acc = 0.f;
        #pragma unroll
        for (int i = 0; i < 8; i++)
            acc += h[(size_t)(base + i) * DIM + d];
        pa[(size_t)bt * DIM + d] = acc;
    }
}

__global__ __launch_bounds__(256) void k_colsum2(const float* __restrict__ pa,
        float* __restrict__ pb) {
    __shared__ float red[4][64];
    int b = blockIdx.x, dt = blockIdx.y;   // grid (2,8)
    int tid = threadIdx.x;
    int c = tid & 63, ig = tid >> 6;
    int d = (dt << 6) + c;
    float s = 0.f;
    for (int i = ig; i < 128; i += 4)
        s += pa[(size_t)(b * 128 + i) * DIM + d];
    red[ig][c] = s;
    __syncthreads();
    if (ig == 0)
        pb[(size_t)b * DIM + d] = red[0][c] + red[1][c] + red[2][c] + red[3][c];
}

__global__ __launch_bounds__(256) void k_final(const float* __restrict__ pb,
        const float* __restrict__ Wout, float* __restrict__ out) {
    __shared__ float red[4][2];
    int tid = threadIdx.x;
    float acc0 = 0.f, acc1 = 0.f;
    #pragma unroll
    for (int half = 0; half < 2; half++) {
        int d = (half << 8) + tid;
        float w = Wout[d];
        acc0 += pb[d] * w;
        acc1 += pb[DIM + d] * w;
    }
    #pragma unroll
    for (int off = 32; off > 0; off >>= 1) {
        acc0 += __shfl_down(acc0, off);
        acc1 += __shfl_down(acc1, off);
    }
    if ((tid & 63) == 0) { red[tid >> 6][0] = acc0; red[tid >> 6][1] = acc1; }
    __syncthreads();
    if (tid == 0) {
        out[0] = red[0][0] + red[1][0] + red[2][0] + red[3][0];
        out[1] = red[0][1] + red[1][1] + red[2][1] + red[3][1];
    }
}

extern "C" void kernel_launch(void* const* d_in, const int* in_sizes, int n_in,
                              void* d_out, int out_size, void* d_ws, size_t ws_size,
                              hipStream_t stream) {
    const float* x    = (const float*)d_in[0];
    const float* Wi   = (const float*)d_in[1];
    const float* bi   = (const float*)d_in[2];
    const float* Wq   = (const float*)d_in[3];
    const float* bq   = (const float*)d_in[4];
    const float* Wk   = (const float*)d_in[5];
    const float* bk   = (const float*)d_in[6];
    const float* Wv   = (const float*)d_in[7];
    const float* bv   = (const float*)d_in[8];
    const float* Er   = (const float*)d_in[9];
    const float* Wlin = (const float*)d_in[10];
    const float* blin = (const float*)d_in[11];
    const float* lng  = (const float*)d_in[12];
    const float* lnb  = (const float*)d_in[13];
    const float* Wout = (const float*)d_in[14];
    float* out = (float*)d_out;

    float* ws = (float*)d_ws;
    const size_t N1 = 1048576;                       // B*S*D
    float*     h     = ws;                           // [0, 1N)
    _Float16*  hf    = (_Float16*)(ws + N1);         // [1N, 1.5N)
    _Float16*  qh    = (_Float16*)(ws + N1 + N1/2);  // [1.5N, 3N): q,k,v f16
    _Float16*  ah    = (_Float16*)(ws + 3 * N1);     // [3N, 3.5N)
    float*     y     = ws + 3 * N1 + N1/2;           // [3.5N, 4.5N)
    _Float16*  Wqkvt = (_Float16*)(ws + 4 * N1 + N1/2);  // [4.5N, 6N)
    _Float16*  Wlint = (_Float16*)(ws + 6 * N1);         // [6N, 6.5N)
    float*     bqkv  = ws + 6 * N1 + N1/2;               // 6144 floats
    _Float16*  Erh   = (_Float16*)(ws + 6 * N1 + N1/2 + 8192);  // 65536 f16
    float*     pa    = ws + 6 * N1 + N1/2 + 8192 + 32768;       // 131072 floats
    float*     pb    = pa + 131072;                              // 1024 floats

    k_prep_all<<<dim3(2328), dim3(256), 0, stream>>>(Wq, Wk, Wv, Wlin, bq, bk, bv,
            Er, x, Wi, bi, Wqkvt, Wlint, bqkv, Erh, h, hf);
    for (int l = 0; l < NL; l++) {
        k_gemm_qkv<<<dim3(16, 16), dim3(256), 0, stream>>>(
                hf, Wqkvt + (size_t)l * 786432, bqkv + l * 1536, qh);
        k_attn_mfma<<<dim3(NB * NH, 8), dim3(512), 0, stream>>>(
                qh, qh + 1048576, qh + 2097152, Erh + (size_t)l * 16384, ah);
        k_gemm_lin<<<dim3(32, 8), dim3(256), 0, stream>>>(
                ah, Wlint + (size_t)l * 262144, blin + l * 512, y);
        k_ln_gelu_res<<<dim3(512), dim3(256), 0, stream>>>(
                y, lng + l * 512, lnb + l * 512, h, hf);
    }
    k_colsum1<<<dim3(256), dim3(256), 0, stream>>>(h, pa);
    k_colsum2<<<dim3(2, 8), dim3(256), 0, stream>>>(pa, pb);
    k_final<<<dim3(1), dim3(256), 0, stream>>>(pb, Wout, out);
}